// Round 2
// 93.676 us; speedup vs baseline: 1.0167x; 1.0167x over previous
//
#include <hip/hip_runtime.h>
#include <cstdint>
#include <utility>

#ifndef __has_builtin
#define __has_builtin(x) 0
#endif

// Extract bit `off` of x and sign-extend: returns 0 or -1 (all-ones mask).
__device__ __forceinline__ int sbfe1(unsigned x, int off) {
#if __has_builtin(__builtin_amdgcn_sbfe)
    return __builtin_amdgcn_sbfe((int)x, off, 1);
#else
    return ((int)(x << (31 - off))) >> 31;
#endif
}

// ---------------------------------------------------------------------------
// Compile-time mask table, built in 64 per-g chunks so each constexpr
// evaluation stays far under clang's -fconstexpr-steps limit (1M). A single
// whole-table evaluation (~4M steps) silently falls back to dynamic init,
// which __device__ globals forbid (the R1 compile failure).
//
// Word layout for (t, g): 16 pairs (r,q), pi = r*4+q.
//   bit pi    : sign of gp term (1 = negative)
//   bit 16+pi : wedge condition (m subset of i)
//   bit 32+pi : inner condition (m&i==0 or i subset of m)
// where i = 4t+r, m = 4g+q, j = m^i.  Sign: parity of
// sum over set bits p of j of popc(m below p) — incremental prefix popcount,
// bit-identical to the reference's construction.
// ---------------------------------------------------------------------------
struct Row { unsigned long long v[64]; };

constexpr Row build_row(int g) {
    Row row{};
    for (int t = 0; t < 64; ++t) {
        unsigned long long word = 0ull;
        for (int r = 0; r < 4; ++r) {
            for (int q = 0; q < 4; ++q) {
                const int i = 4 * t + r;
                const int m = 4 * g + q;
                const int j = m ^ i;
                const int pi = r * 4 + q;
                int cnt = 0, pb = 0;  // pb = popc(m & ((1<<p)-1))
                for (int p = 0; p < 8; ++p) {
                    if ((j >> p) & 1) cnt += pb;
                    pb += (m >> p) & 1;
                }
                if (cnt & 1)                           word |= (1ull << pi);
                if ((m & ~i) == 0)                     word |= (1ull << (16 + pi));
                if (((m & i) == 0) || ((i & ~m) == 0)) word |= (1ull << (32 + pi));
            }
        }
        row.v[t] = word;
    }
    return row;
}

template <int G>
inline constexpr Row row_v = build_row(G);  // one constexpr eval per g (~60K steps)

struct MaskTbl { unsigned long long v[4096]; };

constexpr void copy_row(MaskTbl& tb, int g, const Row& r) {
    for (int t = 0; t < 64; ++t) tb.v[g * 64 + t] = r.v[t];
}

template <std::size_t... Gs>
constexpr MaskTbl gather(std::index_sequence<Gs...>) {
    MaskTbl tb{};
    ((copy_row(tb, (int)Gs, row_v<(int)Gs>)), ...);  // reads cached constants only
    return tb;
}

// 32 KB static device table — no workspace, no prep kernel. L2-resident
// after the first block touches it.
__device__ constexpr MaskTbl TBL = gather(std::make_index_sequence<64>{});

// 4 rows per block, 512 threads; 8 waves split the m-range (8 groups each).
// Mask extraction amortized over 4 rows: 4 shared ops + 7 ops/row per term.
__global__ __launch_bounds__(512) void clifford_main_kernel(
        const float* __restrict__ A, const float* __restrict__ B,
        float* __restrict__ out) {
    __shared__ float As[4][256];
    __shared__ float Bs[4][256];
    __shared__ unsigned long long masks[4096];  // 32 KB; reused as red[8][4][256]

    const int tid = threadIdx.x;   // 0..511
    const int r0 = blockIdx.x * 4; // rows r0..r0+3

    {
        const int row = tid >> 8;  // 0..1
        const int c = tid & 255;
        As[row][c]     = A[(r0 + row) * 256 + c];
        As[row + 2][c] = A[(r0 + row + 2) * 256 + c];
        Bs[row][c]     = B[(r0 + row) * 256 + c];
        Bs[row + 2][c] = B[(r0 + row + 2) * 256 + c];
    }
#pragma unroll
    for (int k2 = 0; k2 < 8; ++k2)
        masks[k2 * 512 + tid] = TBL.v[k2 * 512 + tid];
    __syncthreads();

    const int w = tid >> 6;  // wave id 0..7: m-range split
    const int t = tid & 63;  // thread owns outputs i = 4t+r

    float acc[4][3][4] = {};  // [row][prod][r]

#pragma unroll 2
    for (int gg = 0; gg < 8; ++gg) {
        const int g = (w << 3) | gg;  // this wave's m-group
        const unsigned long long mw = masks[(g << 6) | t];
        float av[4][4], bv[4][4];
#pragma unroll
        for (int row = 0; row < 4; ++row) {
            const float4 a4 = ((const float4*)As[row])[g ^ t];  // XOR-permuted
            const float4 b4 = ((const float4*)Bs[row])[g];      // broadcast
            av[row][0] = a4.x; av[row][1] = a4.y; av[row][2] = a4.z; av[row][3] = a4.w;
            bv[row][0] = b4.x; bv[row][1] = b4.y; bv[row][2] = b4.z; bv[row][3] = b4.w;
        }
        const unsigned lo = (unsigned)mw;
        const unsigned hi = (unsigned)(mw >> 32);
#pragma unroll
        for (int r = 0; r < 4; ++r) {
#pragma unroll
            for (int u = 0; u < 4; ++u) {
                const int q = u ^ r;          // m = 4g+q pairs with a-elem u
                const int pi = (r << 2) | q;  // static bit position
                const unsigned smask = ((unsigned)sbfe1(lo, pi)) & 0x80000000u;
                const unsigned wm = (unsigned)sbfe1(lo, 16 + pi);
                const unsigned im = (unsigned)sbfe1(hi, pi);
#pragma unroll
                for (int row = 0; row < 4; ++row) {
                    const float p = av[row][u] * bv[row][q];
                    const unsigned pu = __float_as_uint(p) ^ smask;
                    acc[row][0][r] += __uint_as_float(pu);
                    acc[row][1][r] += __uint_as_float(pu & wm);
                    acc[row][2][r] += __uint_as_float(pu & im);
                }
            }
        }
    }

    // Chunked cross-wave reduction reusing the mask LDS (32 KB per pass):
    // red[w][row][r*64 + t] holds acc for component comp = 4t+r.
    float* red = (float*)masks;
#pragma unroll
    for (int p = 0; p < 3; ++p) {
        __syncthreads();
#pragma unroll
        for (int row = 0; row < 4; ++row)
#pragma unroll
            for (int r = 0; r < 4; ++r)
                red[w * 1024 + row * 256 + (r << 6) + t] = acc[row][p][r];
        __syncthreads();
#pragma unroll
        for (int c = 0; c < 2; ++c) {
            const int idx = (c << 9) + tid;  // 0..1023
            const int row = idx >> 8;
            const int comp = idx & 255;
            const int swz = row * 256 + (comp >> 2) + ((comp & 3) << 6);
            float s = 0.f;
#pragma unroll
            for (int ww = 0; ww < 8; ++ww) s += red[ww * 1024 + swz];
            out[p * 262144 + (r0 + row) * 256 + comp] = s;  // [3][1024][256]
        }
    }
}

extern "C" void kernel_launch(void* const* d_in, const int* in_sizes, int n_in,
                              void* d_out, int out_size, void* d_ws, size_t ws_size,
                              hipStream_t stream) {
    const float* A = (const float*)d_in[0];
    const float* B = (const float*)d_in[1];
    float* out = (float*)d_out;
    (void)d_ws; (void)ws_size;  // workspace deliberately unused: avoids ws re-poison traffic

    clifford_main_kernel<<<256, 512, 0, stream>>>(A, B, out);
}